// Round 11
// baseline (367.869 us; speedup 1.0000x reference)
//
#include <hip/hip_runtime.h>
#include <float.h>

#define S_  4096
#define B_  8
#define D_  768
#define H_  12
#define HD_ 64
#define W_  128
#define BH_ 96
#define SB_ 32768

typedef unsigned short u16;
typedef __attribute__((ext_vector_type(8))) short bf16x8;
typedef __attribute__((ext_vector_type(4))) float f32x4;

#define MFMA16(a,b,c) __builtin_amdgcn_mfma_f32_16x16x32_bf16(a,b,c,0,0,0)

// f32 -> bf16 round-to-nearest-even
__device__ __forceinline__ u16 f2bf(float x){
  unsigned int u = __float_as_uint(x);
  return (u16)((u + 0x7FFFu + ((u >> 16) & 1u)) >> 16);
}
__device__ __forceinline__ float bf2f(unsigned int lo16){ return __uint_as_float(lo16 << 16); }
__device__ __forceinline__ float bflo(unsigned int u){ return __uint_as_float(u << 16); }
__device__ __forceinline__ float bfhi(unsigned int u){ return __uint_as_float(u & 0xFFFF0000u); }
__device__ __forceinline__ unsigned int pk2(float a, float b){
  return (unsigned int)f2bf(a) | ((unsigned int)f2bf(b) << 16);
}

// async global->LDS, 16B per lane; LDS dest = wave-uniform base + lane*16 (m97/m104)
__device__ __forceinline__ void gload_lds16(const void* g, void* l){
  __builtin_amdgcn_global_load_lds(
      (const __attribute__((address_space(1))) void*)g,
      (__attribute__((address_space(3))) void*)l, 16, 0, 0);
}

// ---------------- mask format sniffing ----------------
__device__ __forceinline__ bool mask_at(const void* mp, int flag, int idx){
  return flag ? (((const unsigned char*)mp)[idx] != 0)
              : (((const unsigned int*)mp)[idx] != 0u);
}

// ---------------- fused prep: cvt_hidden (2048 blk) + cvt_wT (432 blk) + sniff (1 blk) --
__global__ __launch_bounds__(256) void prep_kernel(
    const float* __restrict__ hid, const float* __restrict__ W0,
    const float* __restrict__ W1, const float* __restrict__ W2,
    const unsigned int* __restrict__ maskw,
    u16* __restrict__ hb, u16* __restrict__ wT, int* __restrict__ flag){
  __shared__ float tile[64][65];
  const int bid = blockIdx.x, t = threadIdx.x;
  if (bid < 2048){
    // hidden f32 -> bf16
    int idx = bid * 256 + t;
    for (int base = idx * 8; base < 25165824; base += 2048 * 256 * 8){
      float4 a = *(const float4*)&hid[base];
      float4 b = *(const float4*)&hid[base + 4];
      uint4 o;
      o.x = pk2(a.x, a.y); o.y = pk2(a.z, a.w);
      o.z = pk2(b.x, b.y); o.w = pk2(b.z, b.w);
      *(uint4*)&hb[base] = o;
    }
  } else if (bid < 2480){
    // W (k-major 768x768 f32) -> WT (n-major bf16), 3 mats
    const int wb = bid - 2048;               // 432 = 3 mats x 12 kt x 12 nt
    const int mat = wb / 144, r2 = wb % 144;
    const int kt0 = (r2 / 12) * 64, nt0 = (r2 % 12) * 64;
    const float* Wsel = mat == 0 ? W0 : (mat == 1 ? W1 : W2);
    { const int row = t >> 2, c16 = (t & 3) * 16;
#pragma unroll
      for (int j = 0; j < 4; ++j){
        float4 v = *(const float4*)&Wsel[(size_t)(kt0 + row) * 768 + nt0 + c16 + j * 4];
        tile[row][c16 + j*4 + 0] = v.x; tile[row][c16 + j*4 + 1] = v.y;
        tile[row][c16 + j*4 + 2] = v.z; tile[row][c16 + j*4 + 3] = v.w;
      } }
    __syncthreads();
    { const int nl = t >> 2, k16 = (t & 3) * 16;
      unsigned int o[8];
#pragma unroll
      for (int j = 0; j < 8; ++j)
        o[j] = pk2(tile[k16 + 2*j][nl], tile[k16 + 2*j + 1][nl]);
      u16* dst = wT + (size_t)mat * 589824 + (size_t)(nt0 + nl) * 768 + kt0 + k16;
      *(uint4*)dst       = make_uint4(o[0], o[1], o[2], o[3]);
      *(uint4*)(dst + 8) = make_uint4(o[4], o[5], o[6], o[7]); }
  } else {
    // mask format sniff (int32 words vs packed bytes)
    unsigned int* red = (unsigned int*)&tile[0][0];
    unsigned int acc = 0u;
    for (int i = t; i < 8192; i += 256) acc |= maskw[i];
    red[t] = acc;
    __syncthreads();
    for (int s = 128; s > 0; s >>= 1){
      if (t < s) red[t] |= red[t + s];
      __syncthreads();
    }
    if (t == 0){
      unsigned int o = red[0];
      *flag = (o > 1u && (o & 0xFEFEFEFEu) == 0u) ? 1 : 0;
    }
  }
}

// ---------------- fused 3-projection MFMA GEMM (R9 2-phase counted-vmcnt) -------------
// NEW: p==2 epilogue also writes vtb (V-transpose) straight from the LDS C tile —
// bit-identical to the old vt_kernel output, kills its 100MB round trip.
__global__ __launch_bounds__(256) void proj_mfma_kernel(
    const u16* __restrict__ hb, const u16* __restrict__ wT,
    const float* __restrict__ bq, const float* __restrict__ bk, const float* __restrict__ bv,
    u16* __restrict__ qb, u16* __restrict__ kb, u16* __restrict__ vb,
    u16* __restrict__ vtb){
  __shared__ union ShMem {
    struct { u16 A0[8192]; u16 B0[8192]; u16 A1[8192]; u16 B1[8192]; } ab;  // 65536 B
    u16 C[128 * 130];                                                       // 33280 B
  } sh;
  const int t = threadIdx.x;
  const int id = blockIdx.x;
  const int xcd = id & 7, loc = id >> 3;    // 576 blocks per XCD
  const int nt = loc % 18;                  // nt fastest: 18 blocks share an A panel
  const int mt = xcd * 32 + loc / 18;
  const int p  = nt / 6;
  const int c0 = (nt % 6) * 128;
  const int r0 = mt * 128;
  const float* bias = p == 0 ? bq : (p == 1 ? bk : bv);
  u16* dst = p == 0 ? qb : (p == 1 ? kb : vb);
  const u16* wTp = wT + (size_t)p * 589824;

  const int lane = t & 63, w = t >> 6;
  const int l15 = lane & 15, lg = lane >> 4;
  const int wr = w >> 1, wc = w & 1;
  const int lrc = lane >> 3, slot = lane & 7;   // staging row-in-chunk / 16B slot

  f32x4 acc[4][4] = {};

#define PSTAGE(AS, BS, kof) do{ \
    _Pragma("unroll") \
    for (int c = 0; c < 4; ++c){ \
      int chunk = w * 4 + c; \
      int ldsrow = chunk * 8 + lrc; \
      int slotg = slot ^ (ldsrow & 7); \
      gload_lds16(&hb [(size_t)(r0 + ldsrow) * 768 + (kof) + slotg * 8], &AS[chunk * 512]); \
      gload_lds16(&wTp[(size_t)(c0 + ldsrow) * 768 + (kof) + slotg * 8], &BS[chunk * 512]); \
    } \
  }while(0)

#define PITER(AS, BS, kof, VNSTR, DOSTAGE) do{ \
    asm volatile("s_waitcnt vmcnt(" VNSTR ")" ::: "memory"); \
    __builtin_amdgcn_sched_barrier(0); \
    __builtin_amdgcn_s_barrier(); \
    bf16x8 af[4][2], bf[4][2]; \
    _Pragma("unroll") \
    for (int mf = 0; mf < 4; ++mf) \
      _Pragma("unroll") \
      for (int ks = 0; ks < 2; ++ks) \
        af[mf][ks] = *(const bf16x8*)&AS[(wr*64 + mf*16 + l15) * 64 + (((ks*4 + lg) ^ (l15 & 7)) * 8)]; \
    _Pragma("unroll") \
    for (int nf = 0; nf < 4; ++nf) \
      _Pragma("unroll") \
      for (int ks = 0; ks < 2; ++ks) \
        bf[nf][ks] = *(const bf16x8*)&BS[(wc*64 + nf*16 + l15) * 64 + (((ks*4 + lg) ^ (l15 & 7)) * 8)]; \
    asm volatile("s_waitcnt lgkmcnt(0)" ::: "memory"); \
    __builtin_amdgcn_sched_barrier(0); \
    __builtin_amdgcn_s_barrier(); \
    if (DOSTAGE) PSTAGE(AS, BS, (kof) + 128); \
    _Pragma("unroll") \
    for (int ks = 0; ks < 2; ++ks) \
      _Pragma("unroll") \
      for (int mf = 0; mf < 4; ++mf) \
        _Pragma("unroll") \
        for (int nf = 0; nf < 4; ++nf) \
          acc[mf][nf] = MFMA16(af[mf][ks], bf[nf][ks], acc[mf][nf]); \
  }while(0)

  PSTAGE(sh.ab.A0, sh.ab.B0, 0);
  PSTAGE(sh.ab.A1, sh.ab.B1, 64);
  for (int i2 = 0; i2 < 5; ++i2){
    const int kc = i2 * 128;
    PITER(sh.ab.A0, sh.ab.B0, kc,      "8", 1);
    PITER(sh.ab.A1, sh.ab.B1, kc + 64, "8", 1);
  }
  PITER(sh.ab.A0, sh.ab.B0, 640, "8", 0);
  PITER(sh.ab.A1, sh.ab.B1, 704, "0", 0);
#undef PSTAGE
#undef PITER

  // epilogue: acc -> bf16 C tile (stride 130), then (b,hh,sl)-mapped coalesced stores
#pragma unroll
  for (int nf = 0; nf < 4; ++nf){
    int c = c0 + wc*64 + nf*16 + l15;
    float bsv = bias[c];
#pragma unroll
    for (int mf = 0; mf < 4; ++mf)
#pragma unroll
      for (int r = 0; r < 4; ++r)
        sh.C[(wr*64 + mf*16 + lg*4 + r) * 130 + wc*64 + nf*16 + l15] = f2bf(acc[mf][nf][r] + bsv);
  }
  __syncthreads();
  { const int b = t >> 5, hh2 = (t >> 4) & 1, sl = t & 15;
    const int srow0 = r0 >> 3;                  // tile covers 16 s-values x 8 b
    const int hh = (c0 >> 6) + hh2;
    u16* dp = dst + ((size_t)(b * 12 + hh) * 4096 + srow0 + sl) * 64;
    const u16* sp = &sh.C[(sl * 8 + b) * 130 + hh2 * 64];
#pragma unroll
    for (int j = 0; j < 8; ++j)
      *(uint4*)(dp + j*8) = *(const uint4*)(sp + j*8);
  }
  if (p == 2){
    // vtb[bh][d][s] from C: run over 16 s for fixed (b, head, d). Bit-identical to
    // old vt_kernel (same f2bf values, bit-copy pack).
    const int ri0 = t * 4;
#pragma unroll
    for (int j = 0; j < 4; ++j){
      const int ri = ri0 + j;                    // 0..1023 = (b, hh2, dd)
      const int b = ri >> 7, hh2 = (ri >> 6) & 1, dd = ri & 63;
      unsigned int o[8];
#pragma unroll
      for (int q = 0; q < 8; ++q){
        unsigned int lo = sh.C[((2*q    )*8 + b) * 130 + hh2*64 + dd];
        unsigned int hi = sh.C[((2*q + 1)*8 + b) * 130 + hh2*64 + dd];
        o[q] = lo | (hi << 16);
      }
      u16* dp2 = vtb + ((size_t)((b*12 + (c0 >> 6) + hh2) * 64) + dd) * 4096 + (r0 >> 3);
      *(uint4*)dp2       = make_uint4(o[0], o[1], o[2], o[3]);
      *(uint4*)(dp2 + 8) = make_uint4(o[4], o[5], o[6], o[7]);
    }
  }
}

// ---------------- local windowed attention: swapped-QK^T in-register softmax (R10) ----
__global__ __launch_bounds__(256) void local_mfma_kernel(
    const u16* __restrict__ qb, const u16* __restrict__ kb, const u16* __restrict__ vtb,
    const void* __restrict__ maskp, const int* __restrict__ flagp,
    float* __restrict__ out){
  __shared__ u16 KsA[64 * 64], KsB[64 * 64];
  __shared__ u16 VsA[64 * 64], VsB[64 * 64];
  __shared__ u16 Ps[4][32][72];
  __shared__ float kpen[384];
  __shared__ float qpen_s[128];
  const int t = threadIdx.x;
  const int id = blockIdx.x;
  const int swz = (id & 7) * 384 + (id >> 3);   // 12 bh-groups x 32 windows per XCD
  const int n_i = swz & 31, bh = swz >> 5;
  const int b_i = bh / 12, h = bh % 12;
  const int flag = *flagp;
  const int w = t >> 6, lane = t & 63, l15 = lane & 15, lg = lane >> 4;
  const int lrc = lane >> 3, slot = lane & 7;
  const int jbase0 = n_i * 128 - 128;
  const int jt_lo = (n_i == 0) ? 2 : 0;
  const int jt_hi = (n_i == 31) ? 4 : 6;        // count always even (4 or 6)

#define STAGE_TILE(KS, VS, jtv) do{ \
    int jb_ = jbase0 + (jtv) * 64; \
    _Pragma("unroll") \
    for (int c = 0; c < 2; ++c){ \
      int chunk = w * 2 + c; \
      int ldsrow = chunk * 8 + lrc; \
      int slotg = slot ^ (ldsrow & 7); \
      gload_lds16(&kb [((size_t)bh * 4096 + jb_ + ldsrow) * 64 + slotg * 8], &KS[chunk * 512]); \
      gload_lds16(&vtb[((size_t)bh * 64 + ldsrow) * 4096 + jb_ + slotg * 8], &VS[chunk * 512]); \
    } \
  }while(0)

#define COMPUTE_TILE(KS, VS, jtv) do{ \
    f32x4 dt[2][4] = {}; \
    __builtin_amdgcn_s_setprio(1); \
    _Pragma("unroll") \
    for (int ks2 = 0; ks2 < 2; ++ks2) \
      _Pragma("unroll") \
      for (int nf = 0; nf < 4; ++nf){ \
        bf16x8 bk_ = *(const bf16x8*)&KS[(nf*16 + l15) * 64 + (((ks2*4 + lg) ^ (l15 & 7)) * 8)]; \
        dt[0][nf] = MFMA16(bk_, aq[0][ks2], dt[0][nf]);   /* SWAPPED: D[kpos][qrow] */ \
        dt[1][nf] = MFMA16(bk_, aq[1][ks2], dt[1][nf]); \
      } \
    __builtin_amdgcn_s_setprio(0); \
    /* dt[mf][nf][r] = S[qrow=w*32+mf*16+l15][kpos=(jtv)*64+nf*16+lg*4+r] */ \
    _Pragma("unroll") \
    for (int nf = 0; nf < 4; ++nf){ \
      float4 kpv = *(const float4*)&kpen[(jtv)*64 + nf*16 + lg*4]; \
      _Pragma("unroll") \
      for (int mf = 0; mf < 2; ++mf){ \
        dt[mf][nf][0] = (qp2[mf] + kpv.x == 0.f) ? dt[mf][nf][0] * 0.125f : -FLT_MAX; \
        dt[mf][nf][1] = (qp2[mf] + kpv.y == 0.f) ? dt[mf][nf][1] * 0.125f : -FLT_MAX; \
        dt[mf][nf][2] = (qp2[mf] + kpv.z == 0.f) ? dt[mf][nf][2] * 0.125f : -FLT_MAX; \
        dt[mf][nf][3] = (qp2[mf] + kpv.w == 0.f) ? dt[mf][nf][3] * 0.125f : -FLT_MAX; \
      } \
    } \
    _Pragma("unroll") \
    for (int mf = 0; mf < 2; ++mf){ \
      float tm = dt[mf][0][0]; \
      _Pragma("unroll") \
      for (int nf = 0; nf < 4; ++nf) \
        _Pragma("unroll") \
        for (int r = 0; r < 4; ++r) tm = fmaxf(tm, dt[mf][nf][r]); \
      tm = fmaxf(tm, __shfl_xor(tm, 16)); \
      tm = fmaxf(tm, __shfl_xor(tm, 32)); \
      float mold = mrow[mf]; \
      const bool up = (tm > mold + 8.f);        /* defer-max: P bounded by e^8 */ \
      float mnew = up ? tm : mold; \
      mrow[mf] = mnew; \
      float ps = 0.f; \
      _Pragma("unroll") \
      for (int nf = 0; nf < 4; ++nf) \
        _Pragma("unroll") \
        for (int r = 0; r < 4; ++r){ \
          float pv = __expf(dt[mf][nf][r] - mnew);   /* 0-0=0 keeps uniform rows */ \
          ps += pv; \
          Ps[w][mf*16 + l15][nf*16 + lg*4 + r] = f2bf(pv); \
        } \
      float scl_own = up ? __expf(mold - mnew) : 1.0f; \
      ps += __shfl_xor(ps, 16); \
      ps += __shfl_xor(ps, 32); \
      lrow[mf] = lrow[mf] * scl_own + ps; \
      if (__any(up)){                          /* wave-uniform; rare after 1st tile */ \
        _Pragma("unroll") \
        for (int r = 0; r < 4; ++r){ \
          float sr = __shfl(scl_own, lg*4 + r);  /* row (lg*4+r)'s factor from lane l15=row */ \
          _Pragma("unroll") \
          for (int nf = 0; nf < 4; ++nf) O[mf][nf][r] *= sr; \
        } \
      } \
    } \
    __builtin_amdgcn_s_setprio(1); \
    _Pragma("unroll") \
    for (int ks2 = 0; ks2 < 2; ++ks2){ \
      bf16x8 ap0 = *(const bf16x8*)&Ps[w][l15]     [ks2*32 + lg*8]; \
      bf16x8 ap1 = *(const bf16x8*)&Ps[w][16 + l15][ks2*32 + lg*8]; \
      _Pragma("unroll") \
      for (int nf = 0; nf < 4; ++nf){ \
        bf16x8 bv_ = *(const bf16x8*)&VS[(nf*16 + l15) * 64 + (((ks2*4 + lg) ^ (l15 & 7)) * 8)]; \
        O[0][nf] = MFMA16(ap0, bv_, O[0][nf]); \
        O[1][nf] = MFMA16(ap1, bv_, O[1][nf]); \
      } \
    } \
    __builtin_amdgcn_s_setprio(0); \
  }while(0)

  if (t < 128) qpen_s[t] = mask_at(maskp, flag, b_i * 4096 + n_i * 128 + t) ? 1.f : 0.f;
  for (int j = t; j < 384; j += 256){
    int jp = jbase0 + j;
    kpen[j] = (jp < 0 || jp >= 4096 || mask_at(maskp, flag, b_i * 4096 + jp)) ? 1.f : 0.f;
  }

  bf16x8 aq[2][2];
#pragma unroll
  for (int mf = 0; mf < 2; ++mf)
#pragma unroll
    for (int ks = 0; ks < 2; ++ks)
      aq[mf][ks] = *(const bf16x8*)&qb[((size_t)bh * 4096 + n_i*128 + w*32 + mf*16 + l15) * 64 + ks*32 + lg*8];

  STAGE_TILE(KsA, VsA, jt_lo);
  __syncthreads();   // kpen visible + tile A staged

  float qp2[2];
#pragma unroll
  for (int mf = 0; mf < 2; ++mf)
    qp2[mf] = qpen_s[w*32 + mf*16 + l15];      // this thread's softmax q-row

  f32x4 O[2][4] = {};
  float mrow[2] = { -FLT_MAX, -FLT_MAX };
  float lrow[2] = { 0.f, 0.f };

  for (int base = jt_lo; base < jt_hi; base += 2){
    STAGE_TILE(KsB, VsB, base + 1);          // issue next while computing cur
    COMPUTE_TILE(KsA, VsA, base);
    __syncthreads();                         // B ready; all waves done reading A
    if (base + 2 < jt_hi) STAGE_TILE(KsA, VsA, base + 2);
    COMPUTE_TILE(KsB, VsB, base + 1);
    __syncthreads();                         // A ready; all waves done reading B
  }
#undef STAGE_TILE
#undef COMPUTE_TILE

  const float noor = (n_i == 0 || n_i == 31) ? 128.f : 0.f;
#pragma unroll
  for (int mf = 0; mf < 2; ++mf){
    float lf = lrow[mf] + ((mrow[mf] <= -FLT_MAX) ? noor : 0.f);
    float inv_own = 1.f / lf;
#pragma unroll
    for (int r = 0; r < 4; ++r){
      float inv = __shfl(inv_own, lg*4 + r);   // row (lg*4+r)'s denom from lane l15=row
      int srow = n_i*128 + w*32 + mf*16 + lg*4 + r;
      float* op = &out[(size_t)srow * (8 * 768) + b_i * 768 + h * 64];
#pragma unroll
      for (int nf = 0; nf < 4; ++nf)
        op[nf*16 + l15] = O[mf][nf][r] * inv;
    }
  }
}

// ---------------- global token-0 attention: fused gq + split-S partials, then combine --
__global__ __launch_bounds__(256) void gpart_kernel(
    const float* __restrict__ hid, const float* __restrict__ Wgq, const float* __restrict__ bgq,
    const u16* __restrict__ kb, const u16* __restrict__ vb,
    const void* __restrict__ maskp, const int* __restrict__ flagp,
    float* __restrict__ gp_out){
  __shared__ float hs[768];
  __shared__ float gqs[64];
  __shared__ float sc[512];
  __shared__ float red[256];
  const int t = threadIdx.x, bh = blockIdx.x, chunk = blockIdx.y;
  const int b_i = bh / 12, h = bh % 12;
  const int flag = *flagp;

  // gq = (hidden[0,b] @ Wgq + bgq) * 1/8, computed redundantly per chunk-block (~200cy)
  for (int c = t; c < 768; c += 256) hs[c] = hid[(size_t)b_i * 768 + c];
  __syncthreads();
  { const int dd = t & 63, part = t >> 6;
    float acc = 0.f;
    for (int c = part * 192; c < part * 192 + 192; ++c)
      acc += hs[c] * Wgq[(size_t)c * 768 + h * 64 + dd];
    red[t] = acc; }
  __syncthreads();
  if (t < 64)
    gqs[t] = (red[t] + red[t+64] + red[t+128] + red[t+192] + bgq[h*64 + t]) * 0.125f;
  __syncthreads();

#pragma unroll
  for (int i = 0; i < 2; ++i){
    int sl = i * 256 + t;
    int s = chunk * 512 + sl;
    const uint4* kr = (const uint4*)&kb[((size_t)bh * 4096 + s) * 64];
    float dot = 0.f;
#pragma unroll
    for (int u = 0; u < 8; ++u){
      uint4 x = kr[u];
      dot += gqs[u*8+0]*bflo(x.x) + gqs[u*8+1]*bfhi(x.x);
      dot += gqs[u*8+2]*bflo(x.y) + gqs[u*8+3]*bfhi(x.y);
      dot += gqs[u*8+4]*bflo(x.z) + gqs[u*8+5]*bfhi(x.z);
      dot += gqs[u*8+6]*bflo(x.w) + gqs[u*8+7]*bfhi(x.w);
    }
    sc[sl] = mask_at(maskp, flag, b_i * 4096 + s) ? -FLT_MAX : dot;
  }
  __syncthreads();
  float m = fmaxf(sc[t], sc[t + 256]);
  red[t] = m; __syncthreads();
  for (int st = 128; st > 0; st >>= 1){ if (t < st) red[t] = fmaxf(red[t], red[t + st]); __syncthreads(); }
  const float mc = red[0];
  __syncthreads();
  float ls = 0.f;
#pragma unroll
  for (int i = 0; i < 2; ++i){
    int sl = i * 256 + t;
    float p = __expf(sc[sl] - mc);
    sc[sl] = p; ls += p;
  }
  red[t] = ls; __syncthreads();
  for (int st = 128; st > 0; st >>= 1){ if (t < st) red[t] += red[t + st]; __syncthreads(); }
  const float lc = red[0];
  __syncthreads();
  const int dd = t & 63, part = t >> 6;
  float o = 0.f;
  for (int i2 = 0; i2 < 128; ++i2){
    int sl = part * 128 + i2;
    o += sc[sl] * bf2f(vb[((size_t)bh * 4096 + chunk * 512 + sl) * 64 + dd]);
  }
  red[t] = o; __syncthreads();
  float* gp = gp_out + ((size_t)bh * 8 + chunk) * 66;
  if (t == 0){ gp[0] = mc; gp[1] = lc; }
  if (t < 64) gp[2 + t] = red[t] + red[t+64] + red[t+128] + red[t+192];
}

__global__ __launch_bounds__(64) void greduce_kernel(const float* __restrict__ gp_in,
                                                     float* __restrict__ out){
  const int t = threadIdx.x, bh = blockIdx.x, b_i = bh / 12, h = bh % 12;
  const float* gp = gp_in + (size_t)bh * 8 * 66;
  float mg = -FLT_MAX;
#pragma unroll
  for (int c = 0; c < 8; ++c) mg = fmaxf(mg, gp[c * 66]);
  float lg = 0.f, o = 0.f;
#pragma unroll
  for (int c = 0; c < 8; ++c){
    float wv = __expf(gp[c * 66] - mg);
    lg += gp[c * 66 + 1] * wv;
    o  += gp[c * 66 + 2 + t] * wv;
  }
  out[(size_t)b_i * 768 + h * 64 + t] = o / lg;
}

// ---------------- launch ----------------
extern "C" void kernel_launch(void* const* d_in, const int* in_sizes, int n_in,
                              void* d_out, int out_size, void* d_ws, size_t ws_size,
                              hipStream_t stream) {
  const float* hid   = (const float*)d_in[0];
  const void*  maskp = d_in[1];
  const float* Wq  = (const float*)d_in[2];
  const float* Wk  = (const float*)d_in[3];
  const float* Wv  = (const float*)d_in[4];
  const float* Wgq = (const float*)d_in[5];
  const float* bq  = (const float*)d_in[6];
  const float* bk  = (const float*)d_in[7];
  const float* bv  = (const float*)d_in[8];
  const float* bgq = (const float*)d_in[9];
  float* out = (float*)d_out;

  char* wsb = (char*)d_ws;
  int* flag   = (int*)wsb;                       // 256 B
  u16* hb     = (u16*)(wsb + 256);               // 50331648 B
  u16* wT     = (u16*)(wsb + 50331904);          // 3538944 B
  u16* qb     = (u16*)(wsb + 53870848);          // 50331648 B
  u16* kb     = (u16*)(wsb + 104202496);         // 50331648 B
  u16* vb     = (u16*)(wsb + 154534144);         // 50331648 B
  u16* vtb    = (u16*)(wsb + 204865792);         // 50331648 B
  float* gpart = (float*)(wsb + 255222016);      // 202752 B  (end ~255.4 MB)

  prep_kernel<<<2481, 256, 0, stream>>>(hid, Wq, Wk, Wv,
                                        (const unsigned int*)maskp, hb, wT, flag);
  proj_mfma_kernel<<<4608, 256, 0, stream>>>(hb, wT, bq, bk, bv, qb, kb, vb, vtb);
  local_mfma_kernel<<<3072, 256, 0, stream>>>(qb, kb, vtb, maskp, flag, out);
  gpart_kernel<<<dim3(96, 8), 256, 0, stream>>>(hid, Wgq, bgq, kb, vb, maskp, flag, gpart);
  greduce_kernel<<<96, 64, 0, stream>>>(gpart, out);
}

// Round 12
// 365.263 us; speedup vs baseline: 1.0071x; 1.0071x over previous
//
#include <hip/hip_runtime.h>
#include <float.h>

#define S_  4096
#define B_  8
#define D_  768
#define H_  12
#define HD_ 64
#define W_  128
#define BH_ 96
#define SB_ 32768

typedef unsigned short u16;
typedef __attribute__((ext_vector_type(8))) short bf16x8;
typedef __attribute__((ext_vector_type(4))) float f32x4;

#define MFMA16(a,b,c) __builtin_amdgcn_mfma_f32_16x16x32_bf16(a,b,c,0,0,0)

// f32 -> bf16 round-to-nearest-even
__device__ __forceinline__ u16 f2bf(float x){
  unsigned int u = __float_as_uint(x);
  return (u16)((u + 0x7FFFu + ((u >> 16) & 1u)) >> 16);
}
__device__ __forceinline__ float bf2f(unsigned int lo16){ return __uint_as_float(lo16 << 16); }
__device__ __forceinline__ float bflo(unsigned int u){ return __uint_as_float(u << 16); }
__device__ __forceinline__ float bfhi(unsigned int u){ return __uint_as_float(u & 0xFFFF0000u); }
__device__ __forceinline__ unsigned int pk2(float a, float b){
  return (unsigned int)f2bf(a) | ((unsigned int)f2bf(b) << 16);
}

// async global->LDS, 16B per lane; LDS dest = wave-uniform base + lane*16 (m97/m104)
__device__ __forceinline__ void gload_lds16(const void* g, void* l){
  __builtin_amdgcn_global_load_lds(
      (const __attribute__((address_space(1))) void*)g,
      (__attribute__((address_space(3))) void*)l, 16, 0, 0);
}

// ---------------- mask format sniffing ----------------
__device__ __forceinline__ bool mask_at(const void* mp, int flag, int idx){
  return flag ? (((const unsigned char*)mp)[idx] != 0)
              : (((const unsigned int*)mp)[idx] != 0u);
}

// ---------------- fused prep: cvt_hidden (2048 blk) + cvt_wT (432 blk) + sniff (1 blk) --
__global__ __launch_bounds__(256) void prep_kernel(
    const float* __restrict__ hid, const float* __restrict__ W0,
    const float* __restrict__ W1, const float* __restrict__ W2,
    const unsigned int* __restrict__ maskw,
    u16* __restrict__ hb, u16* __restrict__ wT, int* __restrict__ flag){
  __shared__ float tile[64][65];
  const int bid = blockIdx.x, t = threadIdx.x;
  if (bid < 2048){
    int idx = bid * 256 + t;
    for (int base = idx * 8; base < 25165824; base += 2048 * 256 * 8){
      float4 a = *(const float4*)&hid[base];
      float4 b = *(const float4*)&hid[base + 4];
      uint4 o;
      o.x = pk2(a.x, a.y); o.y = pk2(a.z, a.w);
      o.z = pk2(b.x, b.y); o.w = pk2(b.z, b.w);
      *(uint4*)&hb[base] = o;
    }
  } else if (bid < 2480){
    const int wb = bid - 2048;               // 432 = 3 mats x 12 kt x 12 nt
    const int mat = wb / 144, r2 = wb % 144;
    const int kt0 = (r2 / 12) * 64, nt0 = (r2 % 12) * 64;
    const float* Wsel = mat == 0 ? W0 : (mat == 1 ? W1 : W2);
    { const int row = t >> 2, c16 = (t & 3) * 16;
#pragma unroll
      for (int j = 0; j < 4; ++j){
        float4 v = *(const float4*)&Wsel[(size_t)(kt0 + row) * 768 + nt0 + c16 + j * 4];
        tile[row][c16 + j*4 + 0] = v.x; tile[row][c16 + j*4 + 1] = v.y;
        tile[row][c16 + j*4 + 2] = v.z; tile[row][c16 + j*4 + 3] = v.w;
      } }
    __syncthreads();
    { const int nl = t >> 2, k16 = (t & 3) * 16;
      unsigned int o[8];
#pragma unroll
      for (int j = 0; j < 8; ++j)
        o[j] = pk2(tile[k16 + 2*j][nl], tile[k16 + 2*j + 1][nl]);
      u16* dst = wT + (size_t)mat * 589824 + (size_t)(nt0 + nl) * 768 + kt0 + k16;
      *(uint4*)dst       = make_uint4(o[0], o[1], o[2], o[3]);
      *(uint4*)(dst + 8) = make_uint4(o[4], o[5], o[6], o[7]); }
  } else {
    unsigned int* red = (unsigned int*)&tile[0][0];
    unsigned int acc = 0u;
    for (int i = t; i < 8192; i += 256) acc |= maskw[i];
    red[t] = acc;
    __syncthreads();
    for (int s = 128; s > 0; s >>= 1){
      if (t < s) red[t] |= red[t + s];
      __syncthreads();
    }
    if (t == 0){
      unsigned int o = red[0];
      *flag = (o > 1u && (o & 0xFEFEFEFEu) == 0u) ? 1 : 0;
    }
  }
}

// ---------------- fused 3-projection MFMA GEMM: 128x256 tile, wave-tile 64x128 --------
// LDS-BW analysis (R9-R11: MfmaUtil capped ~28% = 512 B LDS-read per MFMA): wave-tile
// 64x128 reads 12 b128 per 32 MFMA (375 B/MFMA) -> ceiling ~41%. b-FIXED M-tiles
// (rows (s0+i)*8+b0): qb/kb/vb stores 16KB-contiguous, vtb 256B runs (R11 was 32B).
// Same counted-vmcnt 2-phase skeleton (now 12 loads/thread/tile), same XOR swizzle.
__global__ __launch_bounds__(256) void proj_mfma_kernel(
    const u16* __restrict__ hb, const u16* __restrict__ wT,
    const float* __restrict__ bq, const float* __restrict__ bk, const float* __restrict__ bv,
    u16* __restrict__ qb, u16* __restrict__ kb, u16* __restrict__ vb,
    u16* __restrict__ vtb){
  __shared__ union ShMem {
    struct { u16 A0[8192]; u16 B0[16384]; u16 A1[8192]; u16 B1[16384]; } ab; // 98304 B
    u16 C[128 * 264];                                                        // 67584 B
  } sh;
  const int t = threadIdx.x;
  const int id = blockIdx.x;
  const int xcd = id & 7, loc = id >> 3;    // 288 blocks per XCD (= 32 mt x 9 nt)
  const int nt = loc % 9;                   // nt fastest: 9 blocks share an A panel
  const int mt = xcd * 32 + loc / 9;        // mt>>5 == xcd: one b per XCD
  const int p  = nt / 3;
  const int c0 = (nt % 3) * 256;
  const int b0 = mt >> 5;
  const int s0 = (mt & 31) * 128;
  const float* bias = p == 0 ? bq : (p == 1 ? bk : bv);
  u16* dst = p == 0 ? qb : (p == 1 ? kb : vb);
  const u16* wTp = wT + (size_t)p * 589824;
  const int hhbase = c0 >> 6;               // 4 heads per block

  const int lane = t & 63, w = t >> 6;
  const int l15 = lane & 15, lg = lane >> 4;
  const int wr = w >> 1, wc = w & 1;        // wave-tile: rows wr*64+[0,64), cols wc*128+[0,128)
  const int lrc = lane >> 3, slot = lane & 7;

  f32x4 acc[4][8] = {};

#define PSTAGE(AS, BS, kof) do{ \
    _Pragma("unroll") \
    for (int c = 0; c < 4; ++c){            /* A: 16KB = 16 wave-chunks of 1KB */ \
      int chunk = w * 4 + c; \
      int ldsrow = chunk * 8 + lrc;         /* 0..127 = s-offset */ \
      int slotg = slot ^ (ldsrow & 7); \
      gload_lds16(&hb[((size_t)(s0 + ldsrow) * 8 + b0) * 768 + (kof) + slotg * 8], &AS[chunk * 512]); \
    } \
    _Pragma("unroll") \
    for (int c = 0; c < 8; ++c){            /* B: 32KB = 32 wave-chunks */ \
      int chunk = w * 8 + c; \
      int ldsrow = chunk * 8 + lrc;         /* 0..255 = col */ \
      int slotg = slot ^ (ldsrow & 7); \
      gload_lds16(&wTp[(size_t)(c0 + ldsrow) * 768 + (kof) + slotg * 8], &BS[chunk * 512]); \
    } \
  }while(0)

#define PITER(AS, BS, kof, VNSTR, DOSTAGE) do{ \
    asm volatile("s_waitcnt vmcnt(" VNSTR ")" ::: "memory"); \
    __builtin_amdgcn_sched_barrier(0); \
    __builtin_amdgcn_s_barrier(); \
    bf16x8 af[4][2], bf[8][2]; \
    _Pragma("unroll") \
    for (int mf = 0; mf < 4; ++mf) \
      _Pragma("unroll") \
      for (int ks = 0; ks < 2; ++ks) \
        af[mf][ks] = *(const bf16x8*)&AS[(wr*64 + mf*16 + l15) * 64 + (((ks*4 + lg) ^ (l15 & 7)) * 8)]; \
    _Pragma("unroll") \
    for (int nf = 0; nf < 8; ++nf) \
      _Pragma("unroll") \
      for (int ks = 0; ks < 2; ++ks) \
        bf[nf][ks] = *(const bf16x8*)&BS[(wc*128 + nf*16 + l15) * 64 + (((ks*4 + lg) ^ (l15 & 7)) * 8)]; \
    asm volatile("s_waitcnt lgkmcnt(0)" ::: "memory"); \
    __builtin_amdgcn_sched_barrier(0); \
    __builtin_amdgcn_s_barrier(); \
    if (DOSTAGE) PSTAGE(AS, BS, (kof) + 128); \
    _Pragma("unroll") \
    for (int ks = 0; ks < 2; ++ks) \
      _Pragma("unroll") \
      for (int mf = 0; mf < 4; ++mf) \
        _Pragma("unroll") \
        for (int nf = 0; nf < 8; ++nf) \
          acc[mf][nf] = MFMA16(af[mf][ks], bf[nf][ks], acc[mf][nf]); \
  }while(0)

  PSTAGE(sh.ab.A0, sh.ab.B0, 0);
  PSTAGE(sh.ab.A1, sh.ab.B1, 64);
  for (int i2 = 0; i2 < 5; ++i2){
    const int kc = i2 * 128;
    PITER(sh.ab.A0, sh.ab.B0, kc,      "12", 1);
    PITER(sh.ab.A1, sh.ab.B1, kc + 64, "12", 1);
  }
  PITER(sh.ab.A0, sh.ab.B0, 640, "12", 0);
  PITER(sh.ab.A1, sh.ab.B1, 704, "0", 0);
#undef PSTAGE
#undef PITER
  // NOTE: final PITER's lgkmcnt(0)+s_barrier already guarantees all waves'
  // LDS reads are done -> safe to overwrite the union with C.

  // epilogue: acc -> bf16 C tile [128 s][264], then coalesced stores
#pragma unroll
  for (int nf = 0; nf < 8; ++nf){
    int c = c0 + wc*128 + nf*16 + l15;
    float bsv = bias[c];
#pragma unroll
    for (int mf = 0; mf < 4; ++mf)
#pragma unroll
      for (int r = 0; r < 4; ++r)
        sh.C[(wr*64 + mf*16 + lg*4 + r) * 264 + wc*128 + nf*16 + l15] = f2bf(acc[mf][nf][r] + bsv);
  }
  __syncthreads();
  // qb/kb/vb: 512 tasks (4 hh x 128 srow) of 64 dd = 128B each; srow minor -> 16KB runs
#pragma unroll
  for (int rep = 0; rep < 2; ++rep){
    const int task = rep * 256 + t;
    const int srow = task & 127, hh4 = task >> 7;
    u16* dp = dst + ((size_t)(b0 * 12 + hhbase + hh4) * 4096 + s0 + srow) * 64;
    const u16* sp = &sh.C[srow * 264 + hh4 * 64];
#pragma unroll
    for (int j = 0; j < 8; ++j)
      *(uint4*)(dp + j*8) = *(const uint4*)(sp + j*8);
  }
  if (p == 2){
    // vtb[bh][dd][s]: 512 tasks (4 hh x 64 dd x 2 sHalf) of 64 s = 128B contiguous each
#pragma unroll
    for (int rep = 0; rep < 2; ++rep){
      const int task = rep * 256 + t;
      const int dd = task & 63, sHalf = (task >> 6) & 1, hh4 = task >> 7;
      u16* dp2 = vtb + ((size_t)((b0*12 + hhbase + hh4) * 64) + dd) * 4096 + s0 + sHalf * 64;
#pragma unroll
      for (int q = 0; q < 8; ++q){
        unsigned int ow[4];
#pragma unroll
        for (int j = 0; j < 4; ++j){
          const int srow = sHalf*64 + q*8 + 2*j;
          unsigned int lo = sh.C[srow * 264 + hh4*64 + dd];
          unsigned int hi = sh.C[(srow + 1) * 264 + hh4*64 + dd];
          ow[j] = lo | (hi << 16);
        }
        *(uint4*)(dp2 + q*8) = make_uint4(ow[0], ow[1], ow[2], ow[3]);
      }
    }
  }
}

// ---------------- local windowed attention: swapped-QK^T in-register softmax (R10) ----
__global__ __launch_bounds__(256) void local_mfma_kernel(
    const u16* __restrict__ qb, const u16* __restrict__ kb, const u16* __restrict__ vtb,
    const void* __restrict__ maskp, const int* __restrict__ flagp,
    float* __restrict__ out){
  __shared__ u16 KsA[64 * 64], KsB[64 * 64];
  __shared__ u16 VsA[64 * 64], VsB[64 * 64];
  __shared__ u16 Ps[4][32][72];
  __shared__ float kpen[384];
  __shared__ float qpen_s[128];
  const int t = threadIdx.x;
  const int id = blockIdx.x;
  const int swz = (id & 7) * 384 + (id >> 3);   // 12 bh-groups x 32 windows per XCD
  const int n_i = swz & 31, bh = swz >> 5;
  const int b_i = bh / 12, h = bh % 12;
  const int flag = *flagp;
  const int w = t >> 6, lane = t & 63, l15 = lane & 15, lg = lane >> 4;
  const int lrc = lane >> 3, slot = lane & 7;
  const int jbase0 = n_i * 128 - 128;
  const int jt_lo = (n_i == 0) ? 2 : 0;
  const int jt_hi = (n_i == 31) ? 4 : 6;        // count always even (4 or 6)

#define STAGE_TILE(KS, VS, jtv) do{ \
    int jb_ = jbase0 + (jtv) * 64; \
    _Pragma("unroll") \
    for (int c = 0; c < 2; ++c){ \
      int chunk = w * 2 + c; \
      int ldsrow = chunk * 8 + lrc; \
      int slotg = slot ^ (ldsrow & 7); \
      gload_lds16(&kb [((size_t)bh * 4096 + jb_ + ldsrow) * 64 + slotg * 8], &KS[chunk * 512]); \
      gload_lds16(&vtb[((size_t)bh * 64 + ldsrow) * 4096 + jb_ + slotg * 8], &VS[chunk * 512]); \
    } \
  }while(0)

#define COMPUTE_TILE(KS, VS, jtv) do{ \
    f32x4 dt[2][4] = {}; \
    __builtin_amdgcn_s_setprio(1); \
    _Pragma("unroll") \
    for (int ks2 = 0; ks2 < 2; ++ks2) \
      _Pragma("unroll") \
      for (int nf = 0; nf < 4; ++nf){ \
        bf16x8 bk_ = *(const bf16x8*)&KS[(nf*16 + l15) * 64 + (((ks2*4 + lg) ^ (l15 & 7)) * 8)]; \
        dt[0][nf] = MFMA16(bk_, aq[0][ks2], dt[0][nf]);   /* SWAPPED: D[kpos][qrow] */ \
        dt[1][nf] = MFMA16(bk_, aq[1][ks2], dt[1][nf]); \
      } \
    __builtin_amdgcn_s_setprio(0); \
    /* dt[mf][nf][r] = S[qrow=w*32+mf*16+l15][kpos=(jtv)*64+nf*16+lg*4+r] */ \
    _Pragma("unroll") \
    for (int nf = 0; nf < 4; ++nf){ \
      float4 kpv = *(const float4*)&kpen[(jtv)*64 + nf*16 + lg*4]; \
      _Pragma("unroll") \
      for (int mf = 0; mf < 2; ++mf){ \
        dt[mf][nf][0] = (qp2[mf] + kpv.x == 0.f) ? dt[mf][nf][0] * 0.125f : -FLT_MAX; \
        dt[mf][nf][1] = (qp2[mf] + kpv.y == 0.f) ? dt[mf][nf][1] * 0.125f : -FLT_MAX; \
        dt[mf][nf][2] = (qp2[mf] + kpv.z == 0.f) ? dt[mf][nf][2] * 0.125f : -FLT_MAX; \
        dt[mf][nf][3] = (qp2[mf] + kpv.w == 0.f) ? dt[mf][nf][3] * 0.125f : -FLT_MAX; \
      } \
    } \
    _Pragma("unroll") \
    for (int mf = 0; mf < 2; ++mf){ \
      float tm = dt[mf][0][0]; \
      _Pragma("unroll") \
      for (int nf = 0; nf < 4; ++nf) \
        _Pragma("unroll") \
        for (int r = 0; r < 4; ++r) tm = fmaxf(tm, dt[mf][nf][r]); \
      tm = fmaxf(tm, __shfl_xor(tm, 16)); \
      tm = fmaxf(tm, __shfl_xor(tm, 32)); \
      float mold = mrow[mf]; \
      const bool up = (tm > mold + 8.f);        /* defer-max: P bounded by e^8 */ \
      float mnew = up ? tm : mold; \
      mrow[mf] = mnew; \
      float ps = 0.f; \
      _Pragma("unroll") \
      for (int nf = 0; nf < 4; ++nf) \
        _Pragma("unroll") \
        for (int r = 0; r < 4; ++r){ \
          float pv = __expf(dt[mf][nf][r] - mnew);   /* 0-0=0 keeps uniform rows */ \
          ps += pv; \
          Ps[w][mf*16 + l15][nf*16 + lg*4 + r] = f2bf(pv); \
        } \
      float scl_own = up ? __expf(mold - mnew) : 1.0f; \
      ps += __shfl_xor(ps, 16); \
      ps += __shfl_xor(ps, 32); \
      lrow[mf] = lrow[mf] * scl_own + ps; \
      if (__any(up)){                          /* wave-uniform; rare after 1st tile */ \
        _Pragma("unroll") \
        for (int r = 0; r < 4; ++r){ \
          float sr = __shfl(scl_own, lg*4 + r); \
          _Pragma("unroll") \
          for (int nf = 0; nf < 4; ++nf) O[mf][nf][r] *= sr; \
        } \
      } \
    } \
    __builtin_amdgcn_s_setprio(1); \
    _Pragma("unroll") \
    for (int ks2 = 0; ks2 < 2; ++ks2){ \
      bf16x8 ap0 = *(const bf16x8*)&Ps[w][l15]     [ks2*32 + lg*8]; \
      bf16x8 ap1 = *(const bf16x8*)&Ps[w][16 + l15][ks2*32 + lg*8]; \
      _Pragma("unroll") \
      for (int nf = 0; nf < 4; ++nf){ \
        bf16x8 bv_ = *(const bf16x8*)&VS[(nf*16 + l15) * 64 + (((ks2*4 + lg) ^ (l15 & 7)) * 8)]; \
        O[0][nf] = MFMA16(ap0, bv_, O[0][nf]); \
        O[1][nf] = MFMA16(ap1, bv_, O[1][nf]); \
      } \
    } \
    __builtin_amdgcn_s_setprio(0); \
  }while(0)

  if (t < 128) qpen_s[t] = mask_at(maskp, flag, b_i * 4096 + n_i * 128 + t) ? 1.f : 0.f;
  for (int j = t; j < 384; j += 256){
    int jp = jbase0 + j;
    kpen[j] = (jp < 0 || jp >= 4096 || mask_at(maskp, flag, b_i * 4096 + jp)) ? 1.f : 0.f;
  }

  bf16x8 aq[2][2];
#pragma unroll
  for (int mf = 0; mf < 2; ++mf)
#pragma unroll
    for (int ks = 0; ks < 2; ++ks)
      aq[mf][ks] = *(const bf16x8*)&qb[((size_t)bh * 4096 + n_i*128 + w*32 + mf*16 + l15) * 64 + ks*32 + lg*8];

  STAGE_TILE(KsA, VsA, jt_lo);
  __syncthreads();   // kpen visible + tile A staged

  float qp2[2];
#pragma unroll
  for (int mf = 0; mf < 2; ++mf)
    qp2[mf] = qpen_s[w*32 + mf*16 + l15];      // this thread's softmax q-row

  f32x4 O[2][4] = {};
  float mrow[2] = { -FLT_MAX, -FLT_MAX };
  float lrow[2] = { 0.f, 0.f };

  for (int base = jt_lo; base < jt_hi; base += 2){
    STAGE_TILE(KsB, VsB, base + 1);          // issue next while computing cur
    COMPUTE_TILE(KsA, VsA, base);
    __syncthreads();                         // B ready; all waves done reading A
    if (base + 2 < jt_hi) STAGE_TILE(KsA, VsA, base + 2);
    COMPUTE_TILE(KsB, VsB, base + 1);
    __syncthreads();                         // A ready; all waves done reading B
  }
#undef STAGE_TILE
#undef COMPUTE_TILE

  const float noor = (n_i == 0 || n_i == 31) ? 128.f : 0.f;
#pragma unroll
  for (int mf = 0; mf < 2; ++mf){
    float lf = lrow[mf] + ((mrow[mf] <= -FLT_MAX) ? noor : 0.f);
    float inv_own = 1.f / lf;
#pragma unroll
    for (int r = 0; r < 4; ++r){
      float inv = __shfl(inv_own, lg*4 + r);
      int srow = n_i*128 + w*32 + mf*16 + lg*4 + r;
      float* op = &out[(size_t)srow * (8 * 768) + b_i * 768 + h * 64];
#pragma unroll
      for (int nf = 0; nf < 4; ++nf)
        op[nf*16 + l15] = O[mf][nf][r] * inv;
    }
  }
}

// ---------------- global token-0 attention: fused gq + split-S partials, then combine --
__global__ __launch_bounds__(256) void gpart_kernel(
    const float* __restrict__ hid, const float* __restrict__ Wgq, const float* __restrict__ bgq,
    const u16* __restrict__ kb, const u16* __restrict__ vb,
    const void* __restrict__ maskp, const int* __restrict__ flagp,
    float* __restrict__ gp_out){
  __shared__ float hs[768];
  __shared__ float gqs[64];
  __shared__ float sc[512];
  __shared__ float red[256];
  const int t = threadIdx.x, bh = blockIdx.x, chunk = blockIdx.y;
  const int b_i = bh / 12, h = bh % 12;
  const int flag = *flagp;

  for (int c = t; c < 768; c += 256) hs[c] = hid[(size_t)b_i * 768 + c];
  __syncthreads();
  { const int dd = t & 63, part = t >> 6;
    float acc = 0.f;
    for (int c = part * 192; c < part * 192 + 192; ++c)
      acc += hs[c] * Wgq[(size_t)c * 768 + h * 64 + dd];
    red[t] = acc; }
  __syncthreads();
  if (t < 64)
    gqs[t] = (red[t] + red[t+64] + red[t+128] + red[t+192] + bgq[h*64 + t]) * 0.125f;
  __syncthreads();

#pragma unroll
  for (int i = 0; i < 2; ++i){
    int sl = i * 256 + t;
    int s = chunk * 512 + sl;
    const uint4* kr = (const uint4*)&kb[((size_t)bh * 4096 + s) * 64];
    float dot = 0.f;
#pragma unroll
    for (int u = 0; u < 8; ++u){
      uint4 x = kr[u];
      dot += gqs[u*8+0]*bflo(x.x) + gqs[u*8+1]*bfhi(x.x);
      dot += gqs[u*8+2]*bflo(x.y) + gqs[u*8+3]*bfhi(x.y);
      dot += gqs[u*8+4]*bflo(x.z) + gqs[u*8+5]*bfhi(x.z);
      dot += gqs[u*8+6]*bflo(x.w) + gqs[u*8+7]*bfhi(x.w);
    }
    sc[sl] = mask_at(maskp, flag, b_i * 4096 + s) ? -FLT_MAX : dot;
  }
  __syncthreads();
  float m = fmaxf(sc[t], sc[t + 256]);
  red[t] = m; __syncthreads();
  for (int st = 128; st > 0; st >>= 1){ if (t < st) red[t] = fmaxf(red[t], red[t + st]); __syncthreads(); }
  const float mc = red[0];
  __syncthreads();
  float ls = 0.f;
#pragma unroll
  for (int i = 0; i < 2; ++i){
    int sl = i * 256 + t;
    float p = __expf(sc[sl] - mc);
    sc[sl] = p; ls += p;
  }
  red[t] = ls; __syncthreads();
  for (int st = 128; st > 0; st >>= 1){ if (t < st) red[t] += red[t + st]; __syncthreads(); }
  const float lc = red[0];
  __syncthreads();
  const int dd = t & 63, part = t >> 6;
  float o = 0.f;
  for (int i2 = 0; i2 < 128; ++i2){
    int sl = part * 128 + i2;
    o += sc[sl] * bf2f(vb[((size_t)bh * 4096 + chunk * 512 + sl) * 64 + dd]);
  }
  red[t] = o; __syncthreads();
  float* gp = gp_out + ((size_t)bh * 8 + chunk) * 66;
  if (t == 0){ gp[0] = mc; gp[1] = lc; }
  if (t < 64) gp[2 + t] = red[t] + red[t+64] + red[t+128] + red[t+192];
}

__global__ __launch_bounds__(64) void greduce_kernel(const float* __restrict__ gp_in,
                                                     float* __restrict__ out){
  const int t = threadIdx.x, bh = blockIdx.x, b_i = bh / 12, h = bh % 12;
  const float* gp = gp_in + (size_t)bh * 8 * 66;
  float mg = -FLT_MAX;
#pragma unroll
  for (int c = 0; c < 8; ++c) mg = fmaxf(mg, gp[c * 66]);
  float lg = 0.f, o = 0.f;
#pragma unroll
  for (int c = 0; c < 8; ++c){
    float wv = __expf(gp[c * 66] - mg);
    lg += gp[c * 66 + 1] * wv;
    o  += gp[c * 66 + 2 + t] * wv;
  }
  out[(size_t)b_i * 768 + h * 64 + t] = o / lg;
}

// ---------------- launch ----------------
extern "C" void kernel_launch(void* const* d_in, const int* in_sizes, int n_in,
                              void* d_out, int out_size, void* d_ws, size_t ws_size,
                              hipStream_t stream) {
  const float* hid   = (const float*)d_in[0];
  const void*  maskp = d_in[1];
  const float* Wq  = (const float*)d_in[2];
  const float* Wk  = (const float*)d_in[3];
  const float* Wv  = (const float*)d_in[4];
  const float* Wgq = (const float*)d_in[5];
  const float* bq  = (const float*)d_in[6];
  const float* bk  = (const float*)d_in[7];
  const float* bv  = (const float*)d_in[8];
  const float* bgq = (const float*)d_in[9];
  float* out = (float*)d_out;

  char* wsb = (char*)d_ws;
  int* flag   = (int*)wsb;                       // 256 B
  u16* hb     = (u16*)(wsb + 256);               // 50331648 B
  u16* wT     = (u16*)(wsb + 50331904);          // 3538944 B
  u16* qb     = (u16*)(wsb + 53870848);          // 50331648 B
  u16* kb     = (u16*)(wsb + 104202496);         // 50331648 B
  u16* vb     = (u16*)(wsb + 154534144);         // 50331648 B
  u16* vtb    = (u16*)(wsb + 204865792);         // 50331648 B
  float* gpart = (float*)(wsb + 255222016);      // 202752 B  (end ~255.4 MB)

  prep_kernel<<<2481, 256, 0, stream>>>(hid, Wq, Wk, Wv,
                                        (const unsigned int*)maskp, hb, wT, flag);
  proj_mfma_kernel<<<2304, 256, 0, stream>>>(hb, wT, bq, bk, bv, qb, kb, vb, vtb);
  local_mfma_kernel<<<3072, 256, 0, stream>>>(qb, kb, vtb, maskp, flag, out);
  gpart_kernel<<<dim3(96, 8), 256, 0, stream>>>(hid, Wgq, bgq, kb, vb, maskp, flag, gpart);
  greduce_kernel<<<96, 64, 0, stream>>>(gpart, out);
}

// Round 13
// 349.613 us; speedup vs baseline: 1.0522x; 1.0448x over previous
//
#include <hip/hip_runtime.h>
#include <float.h>

#define S_  4096
#define B_  8
#define D_  768
#define H_  12
#define HD_ 64
#define W_  128
#define BH_ 96
#define SB_ 32768

typedef unsigned short u16;
typedef __attribute__((ext_vector_type(8))) short bf16x8;
typedef __attribute__((ext_vector_type(4))) float f32x4;

#define MFMA16(a,b,c) __builtin_amdgcn_mfma_f32_16x16x32_bf16(a,b,c,0,0,0)

// f32 -> bf16 round-to-nearest-even
__device__ __forceinline__ u16 f2bf(float x){
  unsigned int u = __float_as_uint(x);
  return (u16)((u + 0x7FFFu + ((u >> 16) & 1u)) >> 16);
}
__device__ __forceinline__ float bf2f(unsigned int lo16){ return __uint_as_float(lo16 << 16); }
__device__ __forceinline__ float bflo(unsigned int u){ return __uint_as_float(u << 16); }
__device__ __forceinline__ float bfhi(unsigned int u){ return __uint_as_float(u & 0xFFFF0000u); }
__device__ __forceinline__ unsigned int pk2(float a, float b){
  return (unsigned int)f2bf(a) | ((unsigned int)f2bf(b) << 16);
}

// async global->LDS, 16B per lane; LDS dest = wave-uniform base + lane*16 (m97/m104)
__device__ __forceinline__ void gload_lds16(const void* g, void* l){
  __builtin_amdgcn_global_load_lds(
      (const __attribute__((address_space(1))) void*)g,
      (__attribute__((address_space(3))) void*)l, 16, 0, 0);
}

// ---------------- mask format sniffing ----------------
__device__ __forceinline__ bool mask_at(const void* mp, int flag, int idx){
  return flag ? (((const unsigned char*)mp)[idx] != 0)
              : (((const unsigned int*)mp)[idx] != 0u);
}

// ---------------- fused prep: cvt_hidden (2048 blk) + cvt_wT (432 blk) + sniff (1 blk) --
__global__ __launch_bounds__(256) void prep_kernel(
    const float* __restrict__ hid, const float* __restrict__ W0,
    const float* __restrict__ W1, const float* __restrict__ W2,
    const unsigned int* __restrict__ maskw,
    u16* __restrict__ hb, u16* __restrict__ wT, int* __restrict__ flag){
  __shared__ float tile[64][65];
  const int bid = blockIdx.x, t = threadIdx.x;
  if (bid < 2048){
    int idx = bid * 256 + t;
    for (int base = idx * 8; base < 25165824; base += 2048 * 256 * 8){
      float4 a = *(const float4*)&hid[base];
      float4 b = *(const float4*)&hid[base + 4];
      uint4 o;
      o.x = pk2(a.x, a.y); o.y = pk2(a.z, a.w);
      o.z = pk2(b.x, b.y); o.w = pk2(b.z, b.w);
      *(uint4*)&hb[base] = o;
    }
  } else if (bid < 2480){
    const int wb = bid - 2048;               // 432 = 3 mats x 12 kt x 12 nt
    const int mat = wb / 144, r2 = wb % 144;
    const int kt0 = (r2 / 12) * 64, nt0 = (r2 % 12) * 64;
    const float* Wsel = mat == 0 ? W0 : (mat == 1 ? W1 : W2);
    { const int row = t >> 2, c16 = (t & 3) * 16;
#pragma unroll
      for (int j = 0; j < 4; ++j){
        float4 v = *(const float4*)&Wsel[(size_t)(kt0 + row) * 768 + nt0 + c16 + j * 4];
        tile[row][c16 + j*4 + 0] = v.x; tile[row][c16 + j*4 + 1] = v.y;
        tile[row][c16 + j*4 + 2] = v.z; tile[row][c16 + j*4 + 3] = v.w;
      } }
    __syncthreads();
    { const int nl = t >> 2, k16 = (t & 3) * 16;
      unsigned int o[8];
#pragma unroll
      for (int j = 0; j < 8; ++j)
        o[j] = pk2(tile[k16 + 2*j][nl], tile[k16 + 2*j + 1][nl]);
      u16* dst = wT + (size_t)mat * 589824 + (size_t)(nt0 + nl) * 768 + kt0 + k16;
      *(uint4*)dst       = make_uint4(o[0], o[1], o[2], o[3]);
      *(uint4*)(dst + 8) = make_uint4(o[4], o[5], o[6], o[7]); }
  } else {
    unsigned int* red = (unsigned int*)&tile[0][0];
    unsigned int acc = 0u;
    for (int i = t; i < 8192; i += 256) acc |= maskw[i];
    red[t] = acc;
    __syncthreads();
    for (int s = 128; s > 0; s >>= 1){
      if (t < s) red[t] |= red[t + s];
      __syncthreads();
    }
    if (t == 0){
      unsigned int o = red[0];
      *flag = (o > 1u && (o & 0xFEFEFEFEu) == 0u) ? 1 : 0;
    }
  }
}

// ---------------- fused 3-projection MFMA GEMM: R9 128^2 skeleton + b-FIXED M-tiles ----
// R12 lesson: 256-wide tile -> 1 block/CU -> latency exposed (MfmaUtil 25, Occ 10.8).
// Revert to 64KB dbuf (2 blocks/CU, 166us proven). b-fixed M-tiles (b0=xcd,
// s0=(mt&31)*128): C tile spans 128 consecutive s for one b -> vtb runs 128-256B
// contiguous (R11's were 32B scattered), qb/kb/vb stores 128B-coalesced.
__global__ __launch_bounds__(256) void proj_mfma_kernel(
    const u16* __restrict__ hb, const u16* __restrict__ wT,
    const float* __restrict__ bq, const float* __restrict__ bk, const float* __restrict__ bv,
    u16* __restrict__ qb, u16* __restrict__ kb, u16* __restrict__ vb,
    u16* __restrict__ vtb){
  __shared__ union ShMem {
    struct { u16 A0[8192]; u16 B0[8192]; u16 A1[8192]; u16 B1[8192]; } ab;  // 65536 B
    u16 C[128 * 130];                                                       // 33280 B
  } sh;
  const int t = threadIdx.x;
  const int id = blockIdx.x;
  const int xcd = id & 7, loc = id >> 3;    // 576 blocks per XCD
  const int nt = loc % 18;                  // nt fastest: 18 blocks share an A panel
  const int mt = xcd * 32 + loc / 18;
  const int p  = nt / 6;
  const int c0 = (nt % 6) * 128;
  const int b0 = mt >> 5;                   // == xcd (one b per XCD)
  const int s0 = (mt & 31) * 128;
  const float* bias = p == 0 ? bq : (p == 1 ? bk : bv);
  u16* dst = p == 0 ? qb : (p == 1 ? kb : vb);
  const u16* wTp = wT + (size_t)p * 589824;
  const int hhbase = c0 >> 6;               // 2 heads per block

  const int lane = t & 63, w = t >> 6;
  const int l15 = lane & 15, lg = lane >> 4;
  const int wr = w >> 1, wc = w & 1;
  const int lrc = lane >> 3, slot = lane & 7;   // staging row-in-chunk / 16B slot

  f32x4 acc[4][4] = {};

#define PSTAGE(AS, BS, kof) do{ \
    _Pragma("unroll") \
    for (int c = 0; c < 4; ++c){ \
      int chunk = w * 4 + c; \
      int ldsrow = chunk * 8 + lrc;         /* 0..127 = s-offset (b fixed) */ \
      int slotg = slot ^ (ldsrow & 7); \
      gload_lds16(&hb[((size_t)(s0 + ldsrow) * 8 + b0) * 768 + (kof) + slotg * 8], &AS[chunk * 512]); \
      gload_lds16(&wTp[(size_t)(c0 + ldsrow) * 768 + (kof) + slotg * 8], &BS[chunk * 512]); \
    } \
  }while(0)

#define PITER(AS, BS, kof, VNSTR, DOSTAGE) do{ \
    asm volatile("s_waitcnt vmcnt(" VNSTR ")" ::: "memory"); \
    __builtin_amdgcn_sched_barrier(0); \
    __builtin_amdgcn_s_barrier(); \
    bf16x8 af[4][2], bf[4][2]; \
    _Pragma("unroll") \
    for (int mf = 0; mf < 4; ++mf) \
      _Pragma("unroll") \
      for (int ks = 0; ks < 2; ++ks) \
        af[mf][ks] = *(const bf16x8*)&AS[(wr*64 + mf*16 + l15) * 64 + (((ks*4 + lg) ^ (l15 & 7)) * 8)]; \
    _Pragma("unroll") \
    for (int nf = 0; nf < 4; ++nf) \
      _Pragma("unroll") \
      for (int ks = 0; ks < 2; ++ks) \
        bf[nf][ks] = *(const bf16x8*)&BS[(wc*64 + nf*16 + l15) * 64 + (((ks*4 + lg) ^ (l15 & 7)) * 8)]; \
    asm volatile("s_waitcnt lgkmcnt(0)" ::: "memory"); \
    __builtin_amdgcn_sched_barrier(0); \
    __builtin_amdgcn_s_barrier(); \
    if (DOSTAGE) PSTAGE(AS, BS, (kof) + 128); \
    _Pragma("unroll") \
    for (int ks = 0; ks < 2; ++ks) \
      _Pragma("unroll") \
      for (int mf = 0; mf < 4; ++mf) \
        _Pragma("unroll") \
        for (int nf = 0; nf < 4; ++nf) \
          acc[mf][nf] = MFMA16(af[mf][ks], bf[nf][ks], acc[mf][nf]); \
  }while(0)

  PSTAGE(sh.ab.A0, sh.ab.B0, 0);
  PSTAGE(sh.ab.A1, sh.ab.B1, 64);
  for (int i2 = 0; i2 < 5; ++i2){
    const int kc = i2 * 128;
    PITER(sh.ab.A0, sh.ab.B0, kc,      "8", 1);
    PITER(sh.ab.A1, sh.ab.B1, kc + 64, "8", 1);
  }
  PITER(sh.ab.A0, sh.ab.B0, 640, "8", 0);
  PITER(sh.ab.A1, sh.ab.B1, 704, "0", 0);
#undef PSTAGE
#undef PITER
  // final PITER's lgkmcnt(0)+s_barrier: all waves' LDS reads done -> safe union reuse

  // epilogue: acc -> bf16 C tile [128 s][130], rows = consecutive s of one b
#pragma unroll
  for (int nf = 0; nf < 4; ++nf){
    int c = c0 + wc*64 + nf*16 + l15;
    float bsv = bias[c];
#pragma unroll
    for (int mf = 0; mf < 4; ++mf)
#pragma unroll
      for (int r = 0; r < 4; ++r)
        sh.C[(wr*64 + mf*16 + lg*4 + r) * 130 + wc*64 + nf*16 + l15] = f2bf(acc[mf][nf][r] + bsv);
  }
  __syncthreads();
  // qb/kb/vb: 256 tasks (2 hh x 128 srow) of 128B each, s-contiguous
  { const int srow = t & 127, hh2 = t >> 7;
    u16* dp = dst + ((size_t)(b0 * 12 + hhbase + hh2) * 4096 + s0 + srow) * 64;
    const u16* sp = &sh.C[srow * 130 + hh2 * 64];
#pragma unroll
    for (int j = 0; j < 8; ++j)
      *(uint4*)(dp + j*8) = *(const uint4*)(sp + j*8);
  }
  if (p == 2){
    // vtb[bh][dd][s]: 256 tasks = (2 hh x 64 dd) x 2 sHalf; 128B contiguous per task
    const int sHalf = t & 1, pair = t >> 1;
    const int dd = pair & 63, hh2 = pair >> 6;
    u16* dp2 = vtb + ((size_t)((b0*12 + hhbase + hh2) * 64) + dd) * 4096 + s0 + sHalf * 64;
#pragma unroll
    for (int q = 0; q < 8; ++q){
      unsigned int ow[4];
#pragma unroll
      for (int j = 0; j < 4; ++j){
        const int srow = sHalf*64 + q*8 + 2*j;
        unsigned int lo = sh.C[srow * 130 + hh2*64 + dd];
        unsigned int hi = sh.C[(srow + 1) * 130 + hh2*64 + dd];
        ow[j] = lo | (hi << 16);
      }
      *(uint4*)(dp2 + q*8) = make_uint4(ow[0], ow[1], ow[2], ow[3]);
    }
  }
}

// ---------------- local windowed attention: swapped-QK^T + packed Ps writes -----------
__global__ __launch_bounds__(256) void local_mfma_kernel(
    const u16* __restrict__ qb, const u16* __restrict__ kb, const u16* __restrict__ vtb,
    const void* __restrict__ maskp, const int* __restrict__ flagp,
    float* __restrict__ out){
  __shared__ u16 KsA[64 * 64], KsB[64 * 64];
  __shared__ u16 VsA[64 * 64], VsB[64 * 64];
  __shared__ u16 Ps[4][32][72];
  __shared__ float kpen[384];
  __shared__ float qpen_s[128];
  const int t = threadIdx.x;
  const int id = blockIdx.x;
  const int swz = (id & 7) * 384 + (id >> 3);   // 12 bh-groups x 32 windows per XCD
  const int n_i = swz & 31, bh = swz >> 5;
  const int b_i = bh / 12, h = bh % 12;
  const int flag = *flagp;
  const int w = t >> 6, lane = t & 63, l15 = lane & 15, lg = lane >> 4;
  const int lrc = lane >> 3, slot = lane & 7;
  const int jbase0 = n_i * 128 - 128;
  const int jt_lo = (n_i == 0) ? 2 : 0;
  const int jt_hi = (n_i == 31) ? 4 : 6;        // count always even (4 or 6)

#define STAGE_TILE(KS, VS, jtv) do{ \
    int jb_ = jbase0 + (jtv) * 64; \
    _Pragma("unroll") \
    for (int c = 0; c < 2; ++c){ \
      int chunk = w * 2 + c; \
      int ldsrow = chunk * 8 + lrc; \
      int slotg = slot ^ (ldsrow & 7); \
      gload_lds16(&kb [((size_t)bh * 4096 + jb_ + ldsrow) * 64 + slotg * 8], &KS[chunk * 512]); \
      gload_lds16(&vtb[((size_t)bh * 64 + ldsrow) * 4096 + jb_ + slotg * 8], &VS[chunk * 512]); \
    } \
  }while(0)

#define COMPUTE_TILE(KS, VS, jtv) do{ \
    f32x4 dt[2][4] = {}; \
    __builtin_amdgcn_s_setprio(1); \
    _Pragma("unroll") \
    for (int ks2 = 0; ks2 < 2; ++ks2) \
      _Pragma("unroll") \
      for (int nf = 0; nf < 4; ++nf){ \
        bf16x8 bk_ = *(const bf16x8*)&KS[(nf*16 + l15) * 64 + (((ks2*4 + lg) ^ (l15 & 7)) * 8)]; \
        dt[0][nf] = MFMA16(bk_, aq[0][ks2], dt[0][nf]);   /* SWAPPED: D[kpos][qrow] */ \
        dt[1][nf] = MFMA16(bk_, aq[1][ks2], dt[1][nf]); \
      } \
    __builtin_amdgcn_s_setprio(0); \
    /* dt[mf][nf][r] = S[qrow=w*32+mf*16+l15][kpos=(jtv)*64+nf*16+lg*4+r] */ \
    _Pragma("unroll") \
    for (int nf = 0; nf < 4; ++nf){ \
      float4 kpv = *(const float4*)&kpen[(jtv)*64 + nf*16 + lg*4]; \
      _Pragma("unroll") \
      for (int mf = 0; mf < 2; ++mf){ \
        dt[mf][nf][0] = (qp2[mf] + kpv.x == 0.f) ? dt[mf][nf][0] * 0.125f : -FLT_MAX; \
        dt[mf][nf][1] = (qp2[mf] + kpv.y == 0.f) ? dt[mf][nf][1] * 0.125f : -FLT_MAX; \
        dt[mf][nf][2] = (qp2[mf] + kpv.z == 0.f) ? dt[mf][nf][2] * 0.125f : -FLT_MAX; \
        dt[mf][nf][3] = (qp2[mf] + kpv.w == 0.f) ? dt[mf][nf][3] * 0.125f : -FLT_MAX; \
      } \
    } \
    _Pragma("unroll") \
    for (int mf = 0; mf < 2; ++mf){ \
      float tm = dt[mf][0][0]; \
      _Pragma("unroll") \
      for (int nf = 0; nf < 4; ++nf) \
        _Pragma("unroll") \
        for (int r = 0; r < 4; ++r) tm = fmaxf(tm, dt[mf][nf][r]); \
      tm = fmaxf(tm, __shfl_xor(tm, 16)); \
      tm = fmaxf(tm, __shfl_xor(tm, 32)); \
      float mold = mrow[mf]; \
      const bool up = (tm > mold + 8.f);        /* defer-max: P bounded by e^8 */ \
      float mnew = up ? tm : mold; \
      mrow[mf] = mnew; \
      float ps = 0.f; \
      _Pragma("unroll") \
      for (int nf = 0; nf < 4; ++nf){ \
        float pv0 = __expf(dt[mf][nf][0] - mnew); \
        float pv1 = __expf(dt[mf][nf][1] - mnew); \
        float pv2 = __expf(dt[mf][nf][2] - mnew); \
        float pv3 = __expf(dt[mf][nf][3] - mnew); \
        ps += pv0 + pv1 + pv2 + pv3; \
        uint2 w2; w2.x = pk2(pv0, pv1); w2.y = pk2(pv2, pv3); \
        *(uint2*)&Ps[w][mf*16 + l15][nf*16 + lg*4] = w2;   /* 1x8B vs 4x2B */ \
      } \
      float scl_own = up ? __expf(mold - mnew) : 1.0f; \
      ps += __shfl_xor(ps, 16); \
      ps += __shfl_xor(ps, 32); \
      lrow[mf] = lrow[mf] * scl_own + ps; \
      if (__any(up)){                          /* wave-uniform; rare after 1st tile */ \
        _Pragma("unroll") \
        for (int r = 0; r < 4; ++r){ \
          float sr = __shfl(scl_own, lg*4 + r); \
          _Pragma("unroll") \
          for (int nf = 0; nf < 4; ++nf) O[mf][nf][r] *= sr; \
        } \
      } \
    } \
    __builtin_amdgcn_s_setprio(1); \
    _Pragma("unroll") \
    for (int ks2 = 0; ks2 < 2; ++ks2){ \
      bf16x8 ap0 = *(const bf16x8*)&Ps[w][l15]     [ks2*32 + lg*8]; \
      bf16x8 ap1 = *(const bf16x8*)&Ps[w][16 + l15][ks2*32 + lg*8]; \
      _Pragma("unroll") \
      for (int nf = 0; nf < 4; ++nf){ \
        bf16x8 bv_ = *(const bf16x8*)&VS[(nf*16 + l15) * 64 + (((ks2*4 + lg) ^ (l15 & 7)) * 8)]; \
        O[0][nf] = MFMA16(ap0, bv_, O[0][nf]); \
        O[1][nf] = MFMA16(ap1, bv_, O[1][nf]); \
      } \
    } \
    __builtin_amdgcn_s_setprio(0); \
  }while(0)

  if (t < 128) qpen_s[t] = mask_at(maskp, flag, b_i * 4096 + n_i * 128 + t) ? 1.f : 0.f;
  for (int j = t; j < 384; j += 256){
    int jp = jbase0 + j;
    kpen[j] = (jp < 0 || jp >= 4096 || mask_at(maskp, flag, b_i * 4096 + jp)) ? 1.f : 0.f;
  }

  bf16x8 aq[2][2];
#pragma unroll
  for (int mf = 0; mf < 2; ++mf)
#pragma unroll
    for (int ks = 0; ks < 2; ++ks)
      aq[mf][ks] = *(const bf16x8*)&qb[((size_t)bh * 4096 + n_i*128 + w*32 + mf*16 + l15) * 64 + ks*32 + lg*8];

  STAGE_TILE(KsA, VsA, jt_lo);
  __syncthreads();   // kpen visible + tile A staged

  float qp2[2];
#pragma unroll
  for (int mf = 0; mf < 2; ++mf)
    qp2[mf] = qpen_s[w*32 + mf*16 + l15];      // this thread's softmax q-row

  f32x4 O[2][4] = {};
  float mrow[2] = { -FLT_MAX, -FLT_MAX };
  float lrow[2] = { 0.f, 0.f };

  for (int base = jt_lo; base < jt_hi; base += 2){
    STAGE_TILE(KsB, VsB, base + 1);          // issue next while computing cur
    COMPUTE_TILE(KsA, VsA, base);
    __syncthreads();                         // B ready; all waves done reading A
    if (base + 2 < jt_hi) STAGE_TILE(KsA, VsA, base + 2);
    COMPUTE_TILE(KsB, VsB, base + 1);
    __syncthreads();                         // A ready; all waves done reading B
  }
#undef STAGE_TILE
#undef COMPUTE_TILE

  const float noor = (n_i == 0 || n_i == 31) ? 128.f : 0.f;
#pragma unroll
  for (int mf = 0; mf < 2; ++mf){
    float lf = lrow[mf] + ((mrow[mf] <= -FLT_MAX) ? noor : 0.f);
    float inv_own = 1.f / lf;
#pragma unroll
    for (int r = 0; r < 4; ++r){
      float inv = __shfl(inv_own, lg*4 + r);
      int srow = n_i*128 + w*32 + mf*16 + lg*4 + r;
      float* op = &out[(size_t)srow * (8 * 768) + b_i * 768 + h * 64];
#pragma unroll
      for (int nf = 0; nf < 4; ++nf)
        op[nf*16 + l15] = O[mf][nf][r] * inv;
    }
  }
}

// ---------------- global token-0 attention: fused gq + split-S partials, then combine --
__global__ __launch_bounds__(256) void gpart_kernel(
    const float* __restrict__ hid, const float* __restrict__ Wgq, const float* __restrict__ bgq,
    const u16* __restrict__ kb, const u16* __restrict__ vb,
    const void* __restrict__ maskp, const int* __restrict__ flagp,
    float* __restrict__ gp_out){
  __shared__ float hs[768];
  __shared__ float gqs[64];
  __shared__ float sc[512];
  __shared__ float red[256];
  const int t = threadIdx.x, bh = blockIdx.x, chunk = blockIdx.y;
  const int b_i = bh / 12, h = bh % 12;
  const int flag = *flagp;

  for (int c = t; c < 768; c += 256) hs[c] = hid[(size_t)b_i * 768 + c];
  __syncthreads();
  { const int dd = t & 63, part = t >> 6;
    float acc = 0.f;
    for (int c = part * 192; c < part * 192 + 192; ++c)
      acc += hs[c] * Wgq[(size_t)c * 768 + h * 64 + dd];
    red[t] = acc; }
  __syncthreads();
  if (t < 64)
    gqs[t] = (red[t] + red[t+64] + red[t+128] + red[t+192] + bgq[h*64 + t]) * 0.125f;
  __syncthreads();

#pragma unroll
  for (int i = 0; i < 2; ++i){
    int sl = i * 256 + t;
    int s = chunk * 512 + sl;
    const uint4* kr = (const uint4*)&kb[((size_t)bh * 4096 + s) * 64];
    float dot = 0.f;
#pragma unroll
    for (int u = 0; u < 8; ++u){
      uint4 x = kr[u];
      dot += gqs[u*8+0]*bflo(x.x) + gqs[u*8+1]*bfhi(x.x);
      dot += gqs[u*8+2]*bflo(x.y) + gqs[u*8+3]*bfhi(x.y);
      dot += gqs[u*8+4]*bflo(x.z) + gqs[u*8+5]*bfhi(x.z);
      dot += gqs[u*8+6]*bflo(x.w) + gqs[u*8+7]*bfhi(x.w);
    }
    sc[sl] = mask_at(maskp, flag, b_i * 4096 + s) ? -FLT_MAX : dot;
  }
  __syncthreads();
  float m = fmaxf(sc[t], sc[t + 256]);
  red[t] = m; __syncthreads();
  for (int st = 128; st > 0; st >>= 1){ if (t < st) red[t] = fmaxf(red[t], red[t + st]); __syncthreads(); }
  const float mc = red[0];
  __syncthreads();
  float ls = 0.f;
#pragma unroll
  for (int i = 0; i < 2; ++i){
    int sl = i * 256 + t;
    float p = __expf(sc[sl] - mc);
    sc[sl] = p; ls += p;
  }
  red[t] = ls; __syncthreads();
  for (int st = 128; st > 0; st >>= 1){ if (t < st) red[t] += red[t + st]; __syncthreads(); }
  const float lc = red[0];
  __syncthreads();
  const int dd = t & 63, part = t >> 6;
  float o = 0.f;
  for (int i2 = 0; i2 < 128; ++i2){
    int sl = part * 128 + i2;
    o += sc[sl] * bf2f(vb[((size_t)bh * 4096 + chunk * 512 + sl) * 64 + dd]);
  }
  red[t] = o; __syncthreads();
  float* gp = gp_out + ((size_t)bh * 8 + chunk) * 66;
  if (t == 0){ gp[0] = mc; gp[1] = lc; }
  if (t < 64) gp[2 + t] = red[t] + red[t+64] + red[t+128] + red[t+192];
}

__global__ __launch_bounds__(64) void greduce_kernel(const float* __restrict__ gp_in,
                                                     float* __restrict__ out){
  const int t = threadIdx.x, bh = blockIdx.x, b_i = bh / 12, h = bh % 12;
  const float* gp = gp_in + (size_t)bh * 8 * 66;
  float mg = -FLT_MAX;
#pragma unroll
  for (int c = 0; c < 8; ++c) mg = fmaxf(mg, gp[c * 66]);
  float lg = 0.f, o = 0.f;
#pragma unroll
  for (int c = 0; c < 8; ++c){
    float wv = __expf(gp[c * 66] - mg);
    lg += gp[c * 66 + 1] * wv;
    o  += gp[c * 66 + 2 + t] * wv;
  }
  out[(size_t)b_i * 768 + h * 64 + t] = o / lg;
}

// ---------------- launch ----------------
extern "C" void kernel_launch(void* const* d_in, const int* in_sizes, int n_in,
                              void* d_out, int out_size, void* d_ws, size_t ws_size,
                              hipStream_t stream) {
  const float* hid   = (const float*)d_in[0];
  const void*  maskp = d_in[1];
  const float* Wq  = (const float*)d_in[2];
  const float* Wk  = (const float*)d_in[3];
  const float* Wv  = (const float*)d_in[4];
  const float* Wgq = (const float*)d_in[5];
  const float* bq  = (const float*)d_in[6];
  const float* bk  = (const float*)d_in[7];
  const float* bv  = (const float*)d_in[8];
  const float* bgq = (const float*)d_in[9];
  float* out = (float*)d_out;

  char* wsb = (char*)d_ws;
  int* flag   = (int*)wsb;                       // 256 B
  u16* hb     = (u16*)(wsb + 256);               // 50331648 B
  u16* wT     = (u16*)(wsb + 50331904);          // 3538944 B
  u16* qb     = (u16*)(wsb + 53870848);          // 50331648 B
  u16* kb     = (u16*)(wsb + 104202496);         // 50331648 B
  u16* vb     = (u16*)(wsb + 154534144);         // 50331648 B
  u16* vtb    = (u16*)(wsb + 204865792);         // 50331648 B
  float* gpart = (float*)(wsb + 255222016);      // 202752 B  (end ~255.4 MB)

  prep_kernel<<<2481, 256, 0, stream>>>(hid, Wq, Wk, Wv,
                                        (const unsigned int*)maskp, hb, wT, flag);
  proj_mfma_kernel<<<4608, 256, 0, stream>>>(hb, wT, bq, bk, bv, qb, kb, vb, vtb);
  local_mfma_kernel<<<3072, 256, 0, stream>>>(qb, kb, vtb, maskp, flag, out);
  gpart_kernel<<<dim3(96, 8), 256, 0, stream>>>(hid, Wgq, bgq, kb, vb, maskp, flag, gpart);
  greduce_kernel<<<96, 64, 0, stream>>>(gpart, out);
}